// Round 1
// baseline (1837.560 us; speedup 1.0000x reference)
//
#include <hip/hip_runtime.h>

// out layout: (N_VERTICES, 2) row-major fp32: out[2*i] = cbar_i, out[2*i+1] = y_i.

__global__ void vertex_init_kernel(const float* __restrict__ vattr,
                                   float* __restrict__ out, int n) {
    int i = blockIdx.x * blockDim.x + threadIdx.x;
    if (i < n) {
        // vertex_attr is (n, 2); y_i = vattr[i][1]
        float2 va = reinterpret_cast<const float2*>(vattr)[i];
        float2 o = make_float2(0.0f, va.y);
        reinterpret_cast<float2*>(out)[i] = o;
    }
}

__global__ void edge_scatter_kernel(const int* __restrict__ eidx,
                                    const float* __restrict__ eattr,
                                    float* __restrict__ out, int ne4) {
    int tid = blockIdx.x * blockDim.x + threadIdx.x;
    int stride = gridDim.x * blockDim.x;
    for (int i = tid; i < ne4; i += stride) {
        int4   id = reinterpret_cast<const int4*>(eidx)[i];
        float4 v  = reinterpret_cast<const float4*>(eattr)[i];
        atomicAdd(&out[2 * id.x], v.x);
        atomicAdd(&out[2 * id.y], v.y);
        atomicAdd(&out[2 * id.z], v.z);
        atomicAdd(&out[2 * id.w], v.w);
    }
}

extern "C" void kernel_launch(void* const* d_in, const int* in_sizes, int n_in,
                              void* d_out, int out_size, void* d_ws, size_t ws_size,
                              hipStream_t stream) {
    const float* vattr = (const float*)d_in[0];   // (500000, 2) fp32
    const int*   eij   = (const int*)d_in[1];     // (2, 32000000) int32; row 0 = src idx
    const float* eattr = (const float*)d_in[2];   // (32000000, 1) fp32
    float* out = (float*)d_out;                   // (500000, 2) fp32

    const int n_vertices = in_sizes[0] / 2;
    const int n_edges    = in_sizes[2];
    const int ne4        = n_edges / 4;           // 32M divisible by 4

    // Pass 1: zero cbar lane, copy y lane.
    {
        int block = 256;
        int grid = (n_vertices + block - 1) / block;
        vertex_init_kernel<<<grid, block, 0, stream>>>(vattr, out, n_vertices);
    }
    // Pass 2: scatter-add edge_attr into out[2*src].
    {
        int block = 256;
        int grid = 2048;  // ~8 blocks/CU worth of waves; grid-stride covers the rest
        edge_scatter_kernel<<<grid, block, 0, stream>>>(eij, eattr, out, ne4);
    }
}